// Round 1
// baseline (345.321 us; speedup 1.0000x reference)
//
#include <hip/hip_runtime.h>

// Problem constants (fixed by setup_inputs): output (16,2,512,512) f32, target (16,512,512) int32
#define BB   16
#define HH   512
#define WW   512
#define HWSZ (HH * WW)
#define NPIX (BB * HWSZ)
#define LARGE_F 524289.0f  // H*H + W*W + 1, exactly representable in f32

// ---------------- Kernel 1: column-distance (EDT pass 1) for both masks ----------------
// For each pixel, find smallest r >= 0 such that mask(i±r, j) is False.
// pc mask: output[b,1,i,j] > output[b,0,i,j]; gt mask: target[b,i,j] == 1.
// Store r as u16 (0xFFFF = no background in column -> f = LARGE).
__global__ __launch_bounds__(256) void coldist_kernel(
    const float* __restrict__ out4,   // (B,2,H,W)
    const int* __restrict__ target,   // (B,H,W)
    unsigned short* __restrict__ cr_pc,
    unsigned short* __restrict__ cr_gt) {
  int tid = blockIdx.x * blockDim.x + threadIdx.x;
  if (tid >= NPIX) return;
  int b = tid / HWSZ;
  int rem = tid - b * HWSZ;
  int i = rem / WW;
  int j = rem - i * WW;

  const float* x0p = out4 + (size_t)(b * 2) * HWSZ + j;  // channel 0, column j
  const float* x1p = x0p + HWSZ;                          // channel 1
  const int* tp = target + (size_t)b * HWSZ + j;

  // ---- pc column distance ----
  unsigned short rpc = 0xFFFF;
  if (!(x1p[(size_t)i * WW] > x0p[(size_t)i * WW])) {
    rpc = 0;
  } else {
    for (int r = 1; r < HH; ++r) {
      int up = i - r, dn = i + r;
      bool found = false;
      if (up >= 0 && !(x1p[(size_t)up * WW] > x0p[(size_t)up * WW])) found = true;
      if (!found && dn < HH && !(x1p[(size_t)dn * WW] > x0p[(size_t)dn * WW])) found = true;
      if (found) { rpc = (unsigned short)r; break; }
      if (up < 0 && dn >= HH) break;  // no background in this column
    }
  }

  // ---- gt column distance ----
  unsigned short rgt = 0xFFFF;
  if (tp[(size_t)i * WW] != 1) {
    rgt = 0;
  } else {
    for (int r = 1; r < HH; ++r) {
      int up = i - r, dn = i + r;
      bool found = false;
      if (up >= 0 && tp[(size_t)up * WW] != 1) found = true;
      if (!found && dn < HH && tp[(size_t)dn * WW] != 1) found = true;
      if (found) { rgt = (unsigned short)r; break; }
      if (up < 0 && dn >= HH) break;
    }
  }

  cr_pc[tid] = rpc;
  cr_gt[tid] = rgt;
}

// ---------------- Kernel 2: row pass (EDT pass 2) + loss ----------------
__device__ __forceinline__ float fval(unsigned short r) {
  return (r >= 512) ? LARGE_F : (float)((int)r * (int)r);
}

// Exact: candidates at radius r cost >= r^2, so stop once r^2 >= best.
__device__ __forceinline__ float rowmin(const unsigned short* __restrict__ row, int j) {
  float best = fval(row[j]);
  for (int r = 1; r < WW; ++r) {
    float rr = (float)(r * r);
    if (rr >= best) break;
    if (j - r >= 0) best = fminf(best, fval(row[j - r]) + rr);
    if (j + r < WW) best = fminf(best, fval(row[j + r]) + rr);
  }
  return best;
}

__global__ __launch_bounds__(256) void loss_kernel(
    const float* __restrict__ out4,
    const int* __restrict__ target,
    const unsigned short* __restrict__ cr_pc,
    const unsigned short* __restrict__ cr_gt,
    float* __restrict__ d_out) {
  int tid = blockIdx.x * blockDim.x + threadIdx.x;
  float contrib = 0.0f;
  if (tid < NPIX) {
    int b = tid / HWSZ;
    int rem = tid - b * HWSZ;
    int i = rem / WW;
    int j = rem - i * WW;

    const unsigned short* rowpc = cr_pc + (size_t)b * HWSZ + (size_t)i * WW;
    const unsigned short* rowgt = cr_gt + (size_t)b * HWSZ + (size_t)i * WW;
    float dpc = rowmin(rowpc, j);
    float dgt = rowmin(rowgt, j);

    float x0 = out4[(size_t)(b * 2) * HWSZ + rem];
    float x1 = out4[(size_t)(b * 2) * HWSZ + HWSZ + rem];
    float m = fmaxf(x0, x1);
    float e0 = expf(x0 - m), e1 = expf(x1 - m);
    float p1 = e1 / (e0 + e1);
    float y1 = (target[tid] == 1) ? 1.0f : 0.0f;
    float d = p1 - y1;
    contrib = d * d * (dpc + dgt) * (1.0f / (float)NPIX);
  }

  // block reduction: wave shuffle (width 64) then LDS across 4 waves
  for (int off = 32; off > 0; off >>= 1) contrib += __shfl_down(contrib, off);
  __shared__ float ssum[4];
  int lane = threadIdx.x & 63;
  int wave = threadIdx.x >> 6;
  if (lane == 0) ssum[wave] = contrib;
  __syncthreads();
  if (threadIdx.x == 0) {
    float s = ssum[0] + ssum[1] + ssum[2] + ssum[3];
    atomicAdd(d_out, s);
  }
}

extern "C" void kernel_launch(void* const* d_in, const int* in_sizes, int n_in,
                              void* d_out, int out_size, void* d_ws, size_t ws_size,
                              hipStream_t stream) {
  const float* out4 = (const float*)d_in[0];
  const int* target = (const int*)d_in[1];
  unsigned short* cr_pc = (unsigned short*)d_ws;          // 8 MiB
  unsigned short* cr_gt = cr_pc + NPIX;                   // 8 MiB
  float* out = (float*)d_out;

  hipMemsetAsync(d_out, 0, sizeof(float), stream);

  const int threads = 256;
  const int blocks = (NPIX + threads - 1) / threads;  // 16384
  coldist_kernel<<<blocks, threads, 0, stream>>>(out4, target, cr_pc, cr_gt);
  loss_kernel<<<blocks, threads, 0, stream>>>(out4, target, cr_pc, cr_gt, out);
}

// Round 2
// 227.764 us; speedup vs baseline: 1.5161x; 1.5161x over previous
//
#include <hip/hip_runtime.h>

// Problem constants: output (16,2,512,512) f32, target (16,512,512) int32
#define BB   16
#define HH   512
#define WW   512
#define HWSZ (HH * WW)
#define NPIX (BB * HWSZ)
#define LARGE_F 524289.0f  // H*H + W*W + 1
#define WT 32              // columns per coldist block

// ---------------- Kernel 1: column-distance (EDT pass 1), LDS-staged ----------------
// Block = (batch b, 32-column tile). Masks staged as packed bytes in LDS:
// bit0 = pc mask (x1 > x0), bit1 = gt mask (target == 1). Probe smallest r with
// a False at (i±r, c); out-of-range is NOT background (matches scan init LARGE).
__global__ __launch_bounds__(512) void coldist_kernel(
    const float* __restrict__ out4,
    const int* __restrict__ target,
    unsigned short* __restrict__ cr_pc,
    unsigned short* __restrict__ cr_gt) {
  __shared__ unsigned char mbyte[HH * WT];  // 16 KiB

  const int c0 = blockIdx.x * WT;
  const int b  = blockIdx.y;
  const float* ch0 = out4 + (size_t)(b * 2) * HWSZ;
  const float* ch1 = ch0 + HWSZ;
  const int* tb = target + (size_t)b * HWSZ;

  // ---- load phase: 4096 quads (4 px each), 512 threads -> 8 iterations ----
  for (int s = 0; s < 8; ++s) {
    int m  = s * 512 + threadIdx.x;  // quad id in tile
    int i  = m >> 3;                 // 8 quads per tile-row
    int cq = (m & 7) * 4;
    int g  = i * WW + c0 + cq;       // 16B-aligned
    float4 a0 = *(const float4*)(ch0 + g);
    float4 a1 = *(const float4*)(ch1 + g);
    int4   t4 = *(const int4*)(tb + g);
    unsigned int p = 0;
    p |= (unsigned int)(((a1.x > a0.x) ? 1u : 0u) | ((t4.x == 1) ? 2u : 0u));
    p |= (unsigned int)(((a1.y > a0.y) ? 1u : 0u) | ((t4.y == 1) ? 2u : 0u)) << 8;
    p |= (unsigned int)(((a1.z > a0.z) ? 1u : 0u) | ((t4.z == 1) ? 2u : 0u)) << 16;
    p |= (unsigned int)(((a1.w > a0.w) ? 1u : 0u) | ((t4.w == 1) ? 2u : 0u)) << 24;
    *(unsigned int*)&mbyte[i * WT + cq] = p;
  }
  __syncthreads();

  // ---- probe phase: 16384 pixels, 512 threads -> 32 per thread ----
  for (int s = 0; s < 32; ++s) {
    int p = s * 512 + threadIdx.x;
    int i = p >> 5;         // row
    int c = p & 31;         // col within tile
    unsigned char mb = mbyte[p];
    int rpc = (mb & 1) ? -1 : 0;
    int rgt = (mb & 2) ? -1 : 0;
    if ((rpc | rgt) < 0) {
      for (int r = 1; r < HH; ++r) {
        int up = i - r, dn = i + r;
        bool hpc = false, hgt = false;
        if (up >= 0) {
          unsigned char mu = mbyte[up * WT + c];
          hpc |= !(mu & 1); hgt |= !(mu & 2);
        }
        if (dn < HH) {
          unsigned char md = mbyte[dn * WT + c];
          hpc |= !(md & 1); hgt |= !(md & 2);
        }
        if (rpc < 0 && hpc) rpc = r;
        if (rgt < 0 && hgt) rgt = r;
        if ((rpc >= 0 && rgt >= 0) || (up < 0 && dn >= HH)) break;
      }
    }
    size_t gi = (size_t)b * HWSZ + (size_t)i * WW + c0 + c;
    cr_pc[gi] = (rpc < 0) ? 0xFFFF : (unsigned short)rpc;
    cr_gt[gi] = (rgt < 0) ? 0xFFFF : (unsigned short)rgt;
  }
}

// ---------------- Kernel 2: row pass (EDT pass 2) + softmax + loss, LDS-staged ----------------
// One block per (b, i) row; 512 threads, one pixel each.
__global__ __launch_bounds__(512) void loss_kernel(
    const float* __restrict__ out4,
    const int* __restrict__ target,
    const unsigned short* __restrict__ cr_pc,
    const unsigned short* __restrict__ cr_gt,
    float* __restrict__ d_out) {
  __shared__ float fpc[WW];
  __shared__ float fgt[WW];
  __shared__ float ssum[8];

  const int b = blockIdx.x >> 9;
  const int i = blockIdx.x & 511;
  const int j = threadIdx.x;
  const size_t row = (size_t)b * HWSZ + (size_t)i * WW;

  unsigned short rp = cr_pc[row + j];
  unsigned short rg = cr_gt[row + j];
  fpc[j] = (rp >= 512) ? LARGE_F : (float)((int)rp * (int)rp);
  fgt[j] = (rg >= 512) ? LARGE_F : (float)((int)rg * (int)rg);
  __syncthreads();

  // Exact pruned probe: candidates at radius r cost >= r^2, stop when r^2 >= best.
  float bpc = fpc[j];
  float bgt = fgt[j];
  for (int r = 1; r < WW; ++r) {
    float rr = (float)(r * r);
    if (rr >= bpc && rr >= bgt) break;
    int jl = j - r, jr = j + r;
    if (jl >= 0) {
      bpc = fminf(bpc, fpc[jl] + rr);
      bgt = fminf(bgt, fgt[jl] + rr);
    }
    if (jr < WW) {
      bpc = fminf(bpc, fpc[jr] + rr);
      bgt = fminf(bgt, fgt[jr] + rr);
    }
  }

  // loss: p1 = softmax(x)[1] = 1/(1+exp(x0-x1))
  float x0 = out4[(size_t)(b * 2) * HWSZ + (size_t)i * WW + j];
  float x1 = out4[(size_t)(b * 2) * HWSZ + HWSZ + (size_t)i * WW + j];
  float p1 = 1.0f / (1.0f + expf(x0 - x1));
  float y1 = (target[row + j] == 1) ? 1.0f : 0.0f;
  float d = p1 - y1;
  float contrib = d * d * (bpc + bgt) * (1.0f / (float)NPIX);

  // block reduction: wave shuffle (64) then LDS across 8 waves
  for (int off = 32; off > 0; off >>= 1) contrib += __shfl_down(contrib, off);
  int lane = threadIdx.x & 63;
  int wave = threadIdx.x >> 6;
  if (lane == 0) ssum[wave] = contrib;
  __syncthreads();
  if (threadIdx.x == 0) {
    float s = 0.0f;
#pragma unroll
    for (int w = 0; w < 8; ++w) s += ssum[w];
    atomicAdd(d_out, s);
  }
}

extern "C" void kernel_launch(void* const* d_in, const int* in_sizes, int n_in,
                              void* d_out, int out_size, void* d_ws, size_t ws_size,
                              hipStream_t stream) {
  const float* out4 = (const float*)d_in[0];
  const int* target = (const int*)d_in[1];
  unsigned short* cr_pc = (unsigned short*)d_ws;   // 8 MiB
  unsigned short* cr_gt = cr_pc + NPIX;            // 8 MiB
  float* out = (float*)d_out;

  hipMemsetAsync(d_out, 0, sizeof(float), stream);

  dim3 grid1(WW / WT, BB);   // 16 x 16 = 256 blocks
  coldist_kernel<<<grid1, 512, 0, stream>>>(out4, target, cr_pc, cr_gt);

  loss_kernel<<<BB * HH, 512, 0, stream>>>(out4, target, cr_pc, cr_gt, out);
}

// Round 3
// 129.932 us; speedup vs baseline: 2.6577x; 1.7529x over previous
//
#include <hip/hip_runtime.h>

// Problem constants: output (16,2,512,512) f32, target (16,512,512) int32
#define BB   16
#define HH   512
#define WW   512
#define HWSZ (HH * WW)
#define NPIX (BB * HWSZ)
#define LARGE_F 524289.0f  // H*H + W*W + 1
#define WT 16              // columns per coldist block
#define NLOSSBLK (BB * HH) // 8192

// ---------------- Kernel 1: column-distance (EDT pass 1), LDS-staged ----------------
// Block = (16-col tile, batch b). Masks as packed bytes in LDS:
// bit0 = pc mask (x1 > x0), bit1 = gt mask (target == 1). Probe smallest r with
// a False at (i±r, c); out-of-range is NOT background (matches scan init LARGE).
__global__ __launch_bounds__(512) void coldist_kernel(
    const float* __restrict__ out4,
    const int* __restrict__ target,
    unsigned short* __restrict__ cr_pc,
    unsigned short* __restrict__ cr_gt) {
  __shared__ unsigned char mbyte[HH * WT];  // 8 KiB

  const int c0 = blockIdx.x * WT;
  const int b  = blockIdx.y;
  const float* ch0 = out4 + (size_t)(b * 2) * HWSZ;
  const float* ch1 = ch0 + HWSZ;
  const int* tb = target + (size_t)b * HWSZ;

  // ---- load phase: 2048 quads (4 px each), 512 threads -> 4 iterations ----
#pragma unroll
  for (int s = 0; s < 4; ++s) {
    int m  = s * 512 + threadIdx.x;  // quad id in tile
    int i  = m >> 2;                 // 4 quads per tile-row
    int cq = (m & 3) * 4;
    int g  = i * WW + c0 + cq;       // 16B-aligned
    float4 a0 = *(const float4*)(ch0 + g);
    float4 a1 = *(const float4*)(ch1 + g);
    int4   t4 = *(const int4*)(tb + g);
    unsigned int p = 0;
    p |= (unsigned int)(((a1.x > a0.x) ? 1u : 0u) | ((t4.x == 1) ? 2u : 0u));
    p |= (unsigned int)(((a1.y > a0.y) ? 1u : 0u) | ((t4.y == 1) ? 2u : 0u)) << 8;
    p |= (unsigned int)(((a1.z > a0.z) ? 1u : 0u) | ((t4.z == 1) ? 2u : 0u)) << 16;
    p |= (unsigned int)(((a1.w > a0.w) ? 1u : 0u) | ((t4.w == 1) ? 2u : 0u)) << 24;
    *(unsigned int*)&mbyte[i * WT + cq] = p;
  }
  __syncthreads();

  // ---- probe phase: 8192 pixels, 512 threads -> 16 per thread ----
#pragma unroll 1
  for (int s = 0; s < 16; ++s) {
    int p = s * 512 + threadIdx.x;
    int i = p >> 4;         // row
    int c = p & 15;         // col within tile
    unsigned char mb = mbyte[p];
    int rpc = (mb & 1) ? -1 : 0;
    int rgt = (mb & 2) ? -1 : 0;
    if ((rpc | rgt) < 0) {
      for (int r = 1; r < HH; ++r) {
        int up = i - r, dn = i + r;
        bool hpc = false, hgt = false;
        if (up >= 0) {
          unsigned char mu = mbyte[up * WT + c];
          hpc |= !(mu & 1); hgt |= !(mu & 2);
        }
        if (dn < HH) {
          unsigned char md = mbyte[dn * WT + c];
          hpc |= !(md & 1); hgt |= !(md & 2);
        }
        if (rpc < 0 && hpc) rpc = r;
        if (rgt < 0 && hgt) rgt = r;
        if ((rpc >= 0 && rgt >= 0) || (up < 0 && dn >= HH)) break;
      }
    }
    size_t gi = (size_t)b * HWSZ + (size_t)i * WW + c0 + c;
    cr_pc[gi] = (rpc < 0) ? 0xFFFF : (unsigned short)rpc;
    cr_gt[gi] = (rgt < 0) ? 0xFFFF : (unsigned short)rgt;
  }
}

// ---------------- Kernel 2: row pass (EDT pass 2) + softmax + loss ----------------
// One block per (b, i) row; 512 threads, one pixel each. Partial sum -> ws.
__global__ __launch_bounds__(512) void loss_kernel(
    const float* __restrict__ out4,
    const unsigned short* __restrict__ cr_pc,
    const unsigned short* __restrict__ cr_gt,
    float* __restrict__ partials) {
  __shared__ float fpc[WW];
  __shared__ float fgt[WW];
  __shared__ float ssum[8];

  const int b = blockIdx.x >> 9;
  const int i = blockIdx.x & 511;
  const int j = threadIdx.x;
  const size_t row = (size_t)b * HWSZ + (size_t)i * WW;

  unsigned short rp = cr_pc[row + j];
  unsigned short rg = cr_gt[row + j];
  fpc[j] = (rp >= 512) ? LARGE_F : (float)((int)rp * (int)rp);
  fgt[j] = (rg >= 512) ? LARGE_F : (float)((int)rg * (int)rg);
  __syncthreads();

  // Exact pruned probe: candidates at radius r cost >= r^2, stop when r^2 >= best.
  float bpc = fpc[j];
  float bgt = fgt[j];
  for (int r = 1; r < WW; ++r) {
    float rr = (float)(r * r);
    if (rr >= bpc && rr >= bgt) break;
    int jl = j - r, jr = j + r;
    if (jl >= 0) {
      bpc = fminf(bpc, fpc[jl] + rr);
      bgt = fminf(bgt, fgt[jl] + rr);
    }
    if (jr < WW) {
      bpc = fminf(bpc, fpc[jr] + rr);
      bgt = fminf(bgt, fgt[jr] + rr);
    }
  }

  // loss: p1 = softmax(x)[1] = 1/(1+exp(x0-x1)); y1 from gt coldist (rg==0 <=> target!=1)
  float x0 = out4[(size_t)(b * 2) * HWSZ + (size_t)i * WW + j];
  float x1 = out4[(size_t)(b * 2) * HWSZ + HWSZ + (size_t)i * WW + j];
  float p1 = 1.0f / (1.0f + expf(x0 - x1));
  float y1 = (rg != 0) ? 1.0f : 0.0f;
  float d = p1 - y1;
  float contrib = d * d * (bpc + bgt) * (1.0f / (float)NPIX);

  // block reduction: wave shuffle (64) then LDS across 8 waves
  for (int off = 32; off > 0; off >>= 1) contrib += __shfl_down(contrib, off);
  int lane = threadIdx.x & 63;
  int wave = threadIdx.x >> 6;
  if (lane == 0) ssum[wave] = contrib;
  __syncthreads();
  if (threadIdx.x == 0) {
    float s = 0.0f;
#pragma unroll
    for (int w = 0; w < 8; ++w) s += ssum[w];
    partials[blockIdx.x] = s;
  }
}

// ---------------- Kernel 3: final reduce (no atomics) ----------------
__global__ __launch_bounds__(1024) void reduce_kernel(
    const float* __restrict__ partials, float* __restrict__ d_out) {
  __shared__ float ssum[16];
  float s = 0.0f;
#pragma unroll
  for (int k = 0; k < NLOSSBLK / 1024; ++k)
    s += partials[k * 1024 + threadIdx.x];
  for (int off = 32; off > 0; off >>= 1) s += __shfl_down(s, off);
  int lane = threadIdx.x & 63;
  int wave = threadIdx.x >> 6;
  if (lane == 0) ssum[wave] = s;
  __syncthreads();
  if (threadIdx.x == 0) {
    float t = 0.0f;
#pragma unroll
    for (int w = 0; w < 16; ++w) t += ssum[w];
    *d_out = t;
  }
}

extern "C" void kernel_launch(void* const* d_in, const int* in_sizes, int n_in,
                              void* d_out, int out_size, void* d_ws, size_t ws_size,
                              hipStream_t stream) {
  const float* out4 = (const float*)d_in[0];
  const int* target = (const int*)d_in[1];
  unsigned short* cr_pc = (unsigned short*)d_ws;   // 8 MiB
  unsigned short* cr_gt = cr_pc + NPIX;            // 8 MiB
  float* partials = (float*)(cr_gt + NPIX);        // 32 KiB
  float* out = (float*)d_out;

  dim3 grid1(WW / WT, BB);   // 32 x 16 = 512 blocks
  coldist_kernel<<<grid1, 512, 0, stream>>>(out4, target, cr_pc, cr_gt);

  loss_kernel<<<NLOSSBLK, 512, 0, stream>>>(out4, cr_pc, cr_gt, partials);

  reduce_kernel<<<1, 1024, 0, stream>>>(partials, out);
}

// Round 4
// 112.409 us; speedup vs baseline: 3.0720x; 1.1559x over previous
//
#include <hip/hip_runtime.h>

// Problem constants: output (16,2,512,512) f32, target (16,512,512) int32
#define BB   16
#define HH   512
#define WW   512
#define HWSZ (HH * WW)
#define NPIX (BB * HWSZ)
#define LARGE_F 524289.0f  // H*H + W*W + 1
#define WT 16              // columns per coldist block
#define NW 16              // u32 words per column (HH/32)
#define NLOSSBLK (BB * HH / 2)  // 4096 (2 rows per block)

// Column probe on bit-packed masks: distance from row i to nearest 0-bit in
// column c (searching both directions). Returns 0xFFFF if column is all-1.
// bits layout: bits[(c*(NW+1) + w)*2 + sel], pad NW+1 spreads banks (2c+2w).
__device__ __forceinline__ int colprobe(const unsigned int* __restrict__ bits,
                                        int c, int i, int sel) {
  int w = i >> 5, bp = i & 31;
  int cb = c * (NW + 1) * 2 + sel;
  unsigned cur = bits[cb + w * 2];
  unsigned zu = ~cur & (0xFFFFFFFFu >> (31 - bp));  // zero-bits at rows <= i in word
  unsigned zd = ~cur & (0xFFFFFFFFu << bp);         // zero-bits at rows >= i in word
  int up = 0xFFFF, dn = 0xFFFF;
  if (zu) {
    up = bp - (31 - __clz(zu));
  } else {
    for (int ww = w - 1; ww >= 0; --ww) {
      unsigned z = ~bits[cb + ww * 2];
      if (z) { up = i - (ww * 32 + 31 - __clz(z)); break; }
    }
  }
  if (zd) {
    dn = (__ffs(zd) - 1) - bp;
  } else {
    for (int ww = w + 1; ww < NW; ++ww) {
      unsigned z = ~bits[cb + ww * 2];
      if (z) { dn = ww * 32 + (__ffs(z) - 1) - i; break; }
    }
  }
  int r = min(up, dn);
  return min(r, 0xFFFF);
}

// ---------------- Kernel 1: column-distance (EDT pass 1), bit-packed ----------------
// Block = (16-col tile, batch). bit0 = pc mask (x1 > x0), bit1 = gt (target==1).
// Output: combined u32 = rpc | (rgt << 16).
__global__ __launch_bounds__(512) void coldist_kernel(
    const float* __restrict__ out4,
    const int* __restrict__ target,
    unsigned int* __restrict__ cr) {
  __shared__ unsigned char mbyte[HH * WT];           // 8 KiB
  __shared__ unsigned int bits[WT * (NW + 1) * 2];   // 2176 B

  const int c0 = blockIdx.x * WT;
  const int b  = blockIdx.y;
  const float* ch0 = out4 + (size_t)(b * 2) * HWSZ;
  const float* ch1 = ch0 + HWSZ;
  const int* tb = target + (size_t)b * HWSZ;

  // ---- load + mask phase: 2048 quads, 512 threads -> 4 iterations ----
#pragma unroll
  for (int s = 0; s < 4; ++s) {
    int m  = s * 512 + threadIdx.x;
    int i  = m >> 2;                 // 4 quads per tile-row
    int cq = (m & 3) * 4;
    int g  = i * WW + c0 + cq;       // 16B-aligned
    float4 a0 = *(const float4*)(ch0 + g);
    float4 a1 = *(const float4*)(ch1 + g);
    int4   t4 = *(const int4*)(tb + g);
    unsigned p = 0;
    p |= (unsigned)(((a1.x > a0.x) ? 1u : 0u) | ((t4.x == 1) ? 2u : 0u));
    p |= (unsigned)(((a1.y > a0.y) ? 1u : 0u) | ((t4.y == 1) ? 2u : 0u)) << 8;
    p |= (unsigned)(((a1.z > a0.z) ? 1u : 0u) | ((t4.z == 1) ? 2u : 0u)) << 16;
    p |= (unsigned)(((a1.w > a0.w) ? 1u : 0u) | ((t4.w == 1) ? 2u : 0u)) << 24;
    *(unsigned*)&mbyte[i * WT + cq] = p;
  }
  __syncthreads();

  // ---- pack phase: 256 threads, each builds one (pc, gt) word pair ----
  if (threadIdx.x < 256) {
    int c = threadIdx.x >> 4;
    int w = threadIdx.x & 15;
    unsigned pcw = 0, gtw = 0;
    int base = w * 32 * WT + c;
#pragma unroll
    for (int k = 0; k < 32; ++k) {
      unsigned mb = mbyte[base + k * WT];
      pcw |= (mb & 1u) << k;
      gtw |= ((mb >> 1) & 1u) << k;
    }
    bits[(c * (NW + 1) + w) * 2]     = pcw;
    bits[(c * (NW + 1) + w) * 2 + 1] = gtw;
  }
  __syncthreads();

  // ---- probe + store: 8192 pixels, 512 threads -> 16 per thread ----
  unsigned int* crb = cr + (size_t)b * HWSZ;
#pragma unroll 1
  for (int s = 0; s < 16; ++s) {
    int p = s * 512 + threadIdx.x;
    int i = p >> 4;
    int c = p & 15;
    int rpc = colprobe(bits, c, i, 0);
    int rgt = colprobe(bits, c, i, 1);
    crb[i * WW + c0 + c] = (unsigned)rpc | ((unsigned)rgt << 16);
  }
}

// ---------------- Kernel 2: row pass (EDT pass 2) + softmax + loss ----------------
// One block per (b, row-pair); 512 threads. Partial sums -> ws (no atomics).
__global__ __launch_bounds__(512) void loss_kernel(
    const float* __restrict__ out4,
    const unsigned int* __restrict__ cr,
    float* __restrict__ partials) {
  __shared__ float2 f0[WW];
  __shared__ float2 f1[WW];
  __shared__ float ssum[8];

  const int b  = blockIdx.x >> 8;
  const int i0 = (blockIdx.x & 255) * 2;
  const int j  = threadIdx.x;
  const size_t base = (size_t)b * HWSZ + (size_t)i0 * WW;

  unsigned v0 = cr[base + j];
  unsigned v1 = cr[base + WW + j];
  // prefetch logits (consumed after probe; latency hides under it)
  const float* xp = out4 + (size_t)(b * 2) * HWSZ + (size_t)i0 * WW;
  float x00 = xp[j], x01 = xp[WW + j];
  float x10 = xp[HWSZ + j], x11 = xp[HWSZ + WW + j];

  unsigned rp0 = v0 & 0xFFFFu, rg0 = v0 >> 16;
  unsigned rp1 = v1 & 0xFFFFu, rg1 = v1 >> 16;
  float fpc0 = (rp0 >= 512) ? LARGE_F : (float)(rp0 * rp0);
  float fgt0 = (rg0 >= 512) ? LARGE_F : (float)(rg0 * rg0);
  float fpc1 = (rp1 >= 512) ? LARGE_F : (float)(rp1 * rp1);
  float fgt1 = (rg1 >= 512) ? LARGE_F : (float)(rg1 * rg1);
  f0[j] = make_float2(fpc0, fgt0);
  f1[j] = make_float2(fpc1, fgt1);
  __syncthreads();

  // Exact pruned probe (two rows interleaved for ILP):
  // candidates at radius r cost >= r^2, stop when r^2 >= all bests.
  float bpc0 = fpc0, bgt0 = fgt0, bpc1 = fpc1, bgt1 = fgt1;
  for (int r = 1; r < WW; ++r) {
    float rr = (float)(r * r);
    if (rr >= bpc0 && rr >= bgt0 && rr >= bpc1 && rr >= bgt1) break;
    int jl = j - r, jr = j + r;
    if (jl >= 0) {
      float2 a = f0[jl], c2 = f1[jl];
      bpc0 = fminf(bpc0, a.x + rr);  bgt0 = fminf(bgt0, a.y + rr);
      bpc1 = fminf(bpc1, c2.x + rr); bgt1 = fminf(bgt1, c2.y + rr);
    }
    if (jr < WW) {
      float2 a = f0[jr], c2 = f1[jr];
      bpc0 = fminf(bpc0, a.x + rr);  bgt0 = fminf(bgt0, a.y + rr);
      bpc1 = fminf(bpc1, c2.x + rr); bgt1 = fminf(bgt1, c2.y + rr);
    }
  }

  // loss: p1 = 1/(1+exp(x0-x1)); y1 from gt coldist (rg==0 <=> target!=1)
  float p10 = 1.0f / (1.0f + expf(x00 - x10));
  float p11 = 1.0f / (1.0f + expf(x01 - x11));
  float y10 = (rg0 != 0) ? 1.0f : 0.0f;
  float y11 = (rg1 != 0) ? 1.0f : 0.0f;
  float d0 = p10 - y10, d1 = p11 - y11;
  float contrib = (d0 * d0 * (bpc0 + bgt0) + d1 * d1 * (bpc1 + bgt1))
                  * (1.0f / (float)NPIX);

  // block reduction: wave shuffle (64) then LDS across 8 waves
  for (int off = 32; off > 0; off >>= 1) contrib += __shfl_down(contrib, off);
  int lane = threadIdx.x & 63;
  int wave = threadIdx.x >> 6;
  if (lane == 0) ssum[wave] = contrib;
  __syncthreads();
  if (threadIdx.x == 0) {
    float s = 0.0f;
#pragma unroll
    for (int w = 0; w < 8; ++w) s += ssum[w];
    partials[blockIdx.x] = s;
  }
}

// ---------------- Kernel 3: final reduce (no atomics) ----------------
__global__ __launch_bounds__(1024) void reduce_kernel(
    const float* __restrict__ partials, float* __restrict__ d_out) {
  __shared__ float ssum[16];
  float s = 0.0f;
#pragma unroll
  for (int k = 0; k < NLOSSBLK / 1024; ++k)
    s += partials[k * 1024 + threadIdx.x];
  for (int off = 32; off > 0; off >>= 1) s += __shfl_down(s, off);
  int lane = threadIdx.x & 63;
  int wave = threadIdx.x >> 6;
  if (lane == 0) ssum[wave] = s;
  __syncthreads();
  if (threadIdx.x == 0) {
    float t = 0.0f;
#pragma unroll
    for (int w = 0; w < 16; ++w) t += ssum[w];
    *d_out = t;
  }
}

extern "C" void kernel_launch(void* const* d_in, const int* in_sizes, int n_in,
                              void* d_out, int out_size, void* d_ws, size_t ws_size,
                              hipStream_t stream) {
  const float* out4 = (const float*)d_in[0];
  const int* target = (const int*)d_in[1];
  unsigned int* cr = (unsigned int*)d_ws;      // 16 MiB combined (rpc | rgt<<16)
  float* partials = (float*)(cr + NPIX);       // 16 KiB
  float* out = (float*)d_out;

  dim3 grid1(WW / WT, BB);   // 32 x 16 = 512 blocks
  coldist_kernel<<<grid1, 512, 0, stream>>>(out4, target, cr);

  loss_kernel<<<NLOSSBLK, 512, 0, stream>>>(out4, cr, partials);

  reduce_kernel<<<1, 1024, 0, stream>>>(partials, out);
}

// Round 5
// 103.666 us; speedup vs baseline: 3.3311x; 1.0843x over previous
//
#include <hip/hip_runtime.h>

// Problem constants: output (16,2,512,512) f32, target (16,512,512) int32
#define BB   16
#define HH   512
#define WW   512
#define HWSZ (HH * WW)
#define NPIX (BB * HWSZ)
#define LARGE_F 524289.0f  // H*H + W*W + 1
#define NW 16              // u32 words per column (HH/32)
#define GR 4               // rows per loss block
#define NLOSSBLK (BB * HH / GR)  // 2048

// Global bit layout: bitsG[((b*2+sel)*NW + w)*WW + c], bit k of word w = row w*32+k.
// sel 0 = pc mask (x1 > x0), sel 1 = gt mask (target == 1).

// ---------------- Kernel 1: mask pack (transpose to column bitmasks) ----------------
// Block = (band w + col-half, image b). 512 blocks, 512 threads.
__global__ __launch_bounds__(512) void pack_kernel(
    const float* __restrict__ out4,
    const int* __restrict__ target,
    unsigned int* __restrict__ bitsG) {
  __shared__ unsigned char mbyte[32 * 256];  // 8 KiB

  const int w    = blockIdx.x >> 1;   // word-row band (0..15)
  const int half = blockIdx.x & 1;    // col half
  const int b    = blockIdx.y;
  const int c0   = half * 256;
  const float* ch0 = out4 + (size_t)(b * 2) * HWSZ;
  const float* ch1 = ch0 + HWSZ;
  const int* tb = target + (size_t)b * HWSZ;

  // load 32 rows x 256 cols, 2048 quads, 512 threads -> 4 iters
#pragma unroll
  for (int s = 0; s < 4; ++s) {
    int q  = s * 512 + threadIdx.x;
    int i  = q >> 6;            // 64 quads per row
    int cq = (q & 63) * 4;
    int g  = (w * 32 + i) * WW + c0 + cq;
    float4 a0 = *(const float4*)(ch0 + g);
    float4 a1 = *(const float4*)(ch1 + g);
    int4   t4 = *(const int4*)(tb + g);
    unsigned p = 0;
    p |= (unsigned)(((a1.x > a0.x) ? 1u : 0u) | ((t4.x == 1) ? 2u : 0u));
    p |= (unsigned)(((a1.y > a0.y) ? 1u : 0u) | ((t4.y == 1) ? 2u : 0u)) << 8;
    p |= (unsigned)(((a1.z > a0.z) ? 1u : 0u) | ((t4.z == 1) ? 2u : 0u)) << 16;
    p |= (unsigned)(((a1.w > a0.w) ? 1u : 0u) | ((t4.w == 1) ? 2u : 0u)) << 24;
    *(unsigned*)&mbyte[i * 256 + cq] = p;
  }
  __syncthreads();

  // pack: thread t -> column c = t&255, sel = t>>8
  {
    int c   = threadIdx.x & 255;
    int sel = threadIdx.x >> 8;
    unsigned wd = 0;
#pragma unroll
    for (int k = 0; k < 32; ++k) {
      unsigned mb = mbyte[k * 256 + c];
      wd |= ((mb >> sel) & 1u) << k;
    }
    bitsG[(size_t)((b * 2 + sel) * NW + w) * WW + c0 + c] = wd;
  }
}

// Column probe on bit-packed masks in LDS band [wlo..whi] with global fallback.
// Returns distance from row i to nearest 0-bit in the column (0xFFFF if none).
__device__ __forceinline__ int colprobe(const unsigned (*lb)[WW],
                                        const unsigned* __restrict__ gcol,
                                        int wlo, int whi, int j, int i) {
  int w = i >> 5, bp = i & 31;
  unsigned cur = lb[w - wlo][j];
  unsigned zu = ~cur & (0xFFFFFFFFu >> (31 - bp));
  unsigned zd = ~cur & (0xFFFFFFFFu << bp);
  int up = 0xFFFF, dn = 0xFFFF;
  if (zu) {
    up = bp - (31 - __clz(zu));
  } else {
    for (int ww = w - 1; ww >= 0; --ww) {
      unsigned z = ~((ww >= wlo) ? lb[ww - wlo][j] : gcol[ww * WW]);
      if (z) { up = i - (ww * 32 + 31 - __clz(z)); break; }
    }
  }
  if (zd) {
    dn = (__ffs((int)zd) - 1) - bp;
  } else {
    for (int ww = w + 1; ww < NW; ++ww) {
      unsigned z = ~((ww <= whi) ? lb[ww - wlo][j] : gcol[ww * WW]);
      if (z) { dn = ww * 32 + (__ffs((int)z) - 1) - i; break; }
    }
  }
  return min(min(up, dn), 0xFFFF);
}

// ---------------- Kernel 2: col EDT (from bits) + row EDT + softmax + loss ----------------
// Block = 4 rows of one image; 512 threads, one column each.
__global__ __launch_bounds__(512) void loss_kernel(
    const float* __restrict__ out4,
    const unsigned int* __restrict__ bitsG,
    float* __restrict__ partials) {
  __shared__ unsigned lbits[2][5][WW];  // 20 KiB band: [sel][wrel][col]
  __shared__ float2 fv[GR][WW];         // 16 KiB: (fpc, fgt) per row/col
  __shared__ float ssum[8];

  const int b  = blockIdx.x >> 7;
  const int i0 = (blockIdx.x & 127) * GR;
  const int j  = threadIdx.x;

  const int wc  = i0 >> 5;
  const int wlo = max(0, wc - 2);
  const int whi = min(NW - 1, wc + 2);
  const int nwr = whi - wlo + 1;

  // ---- stage bits band: nwr*2 word-rows x 512 cols ----
  const unsigned* gb = bitsG + (size_t)(b * 2) * NW * WW;
  for (int idx = threadIdx.x; idx < nwr * 2 * WW; idx += 512) {
    int c    = idx & (WW - 1);
    int rest = idx >> 9;
    int wrel = rest >> 1;
    int sel  = rest & 1;
    lbits[sel][wrel][c] = gb[(size_t)(sel * NW + wlo + wrel) * WW + c];
  }

  // prefetch logits (consumed after probes)
  const float* xp = out4 + (size_t)(b * 2) * HWSZ + (size_t)i0 * WW;
  float x0v[GR], x1v[GR];
#pragma unroll
  for (int rw = 0; rw < GR; ++rw) {
    x0v[rw] = xp[rw * WW + j];
    x1v[rw] = xp[HWSZ + rw * WW + j];
  }
  __syncthreads();

  // ---- column distances for my column, 4 rows, both masks ----
  const unsigned* gpc = gb + j;
  const unsigned* ggt = gb + NW * WW + j;
  float y1v[GR];
  float bpc[GR], bgt[GR];
#pragma unroll
  for (int rw = 0; rw < GR; ++rw) {
    int i = i0 + rw;
    int rpc = colprobe(lbits[0], gpc, wlo, whi, j, i);
    int rgt = colprobe(lbits[1], ggt, wlo, whi, j, i);
    float fpc = (rpc >= 512) ? LARGE_F : (float)(rpc * rpc);
    float fgt = (rgt >= 512) ? LARGE_F : (float)(rgt * rgt);
    fv[rw][j] = make_float2(fpc, fgt);
    bpc[rw] = fpc; bgt[rw] = fgt;
    y1v[rw] = (rgt != 0) ? 1.0f : 0.0f;  // gt mask bit
  }
  __syncthreads();

  // ---- row pass: exact pruned probe, 4 rows x 2 masks interleaved ----
  for (int r = 1; r < WW; ++r) {
    float rr = (float)(r * r);
    float mx = fmaxf(fmaxf(fmaxf(bpc[0], bgt[0]), fmaxf(bpc[1], bgt[1])),
                     fmaxf(fmaxf(bpc[2], bgt[2]), fmaxf(bpc[3], bgt[3])));
    if (rr >= mx) break;
    int jl = j - r, jr = j + r;
    if (jl >= 0) {
#pragma unroll
      for (int rw = 0; rw < GR; ++rw) {
        float2 a = fv[rw][jl];
        bpc[rw] = fminf(bpc[rw], a.x + rr);
        bgt[rw] = fminf(bgt[rw], a.y + rr);
      }
    }
    if (jr < WW) {
#pragma unroll
      for (int rw = 0; rw < GR; ++rw) {
        float2 a = fv[rw][jr];
        bpc[rw] = fminf(bpc[rw], a.x + rr);
        bgt[rw] = fminf(bgt[rw], a.y + rr);
      }
    }
  }

  // ---- loss ----
  float contrib = 0.0f;
#pragma unroll
  for (int rw = 0; rw < GR; ++rw) {
    float p1 = 1.0f / (1.0f + expf(x0v[rw] - x1v[rw]));
    float d = p1 - y1v[rw];
    contrib += d * d * (bpc[rw] + bgt[rw]);
  }
  contrib *= (1.0f / (float)NPIX);

  // block reduction
  for (int off = 32; off > 0; off >>= 1) contrib += __shfl_down(contrib, off);
  int lane = threadIdx.x & 63;
  int wave = threadIdx.x >> 6;
  if (lane == 0) ssum[wave] = contrib;
  __syncthreads();
  if (threadIdx.x == 0) {
    float s = 0.0f;
#pragma unroll
    for (int w = 0; w < 8; ++w) s += ssum[w];
    partials[blockIdx.x] = s;
  }
}

// ---------------- Kernel 3: final reduce ----------------
__global__ __launch_bounds__(1024) void reduce_kernel(
    const float* __restrict__ partials, float* __restrict__ d_out) {
  __shared__ float ssum[16];
  float s = 0.0f;
#pragma unroll
  for (int k = 0; k < NLOSSBLK / 1024; ++k)
    s += partials[k * 1024 + threadIdx.x];
  for (int off = 32; off > 0; off >>= 1) s += __shfl_down(s, off);
  int lane = threadIdx.x & 63;
  int wave = threadIdx.x >> 6;
  if (lane == 0) ssum[wave] = s;
  __syncthreads();
  if (threadIdx.x == 0) {
    float t = 0.0f;
#pragma unroll
    for (int w = 0; w < 16; ++w) t += ssum[w];
    *d_out = t;
  }
}

extern "C" void kernel_launch(void* const* d_in, const int* in_sizes, int n_in,
                              void* d_out, int out_size, void* d_ws, size_t ws_size,
                              hipStream_t stream) {
  const float* out4 = (const float*)d_in[0];
  const int* target = (const int*)d_in[1];
  unsigned int* bitsG = (unsigned int*)d_ws;              // 1 MiB
  float* partials = (float*)(bitsG + BB * 2 * NW * WW);   // 8 KiB
  float* out = (float*)d_out;

  dim3 grid1(32, BB);  // (band, col-half) x image = 512 blocks
  pack_kernel<<<grid1, 512, 0, stream>>>(out4, target, bitsG);

  loss_kernel<<<NLOSSBLK, 512, 0, stream>>>(out4, bitsG, partials);

  reduce_kernel<<<1, 1024, 0, stream>>>(partials, out);
}